// Round 3
// baseline (152.502 us; speedup 1.0000x reference)
//
#include <hip/hip_runtime.h>
#include <hip/hip_bf16.h>

// ContrastiveLoss: B=8192, D=128, 100 classes.
// loss_i = -log( max(sum_{j!=i, lab_j==lab_i} e^{s_ij},1e-8) / max(sum_{j!=i} e^{s_ij},1e-8) )
// s_ij = clip( f_hat_i . f_hat_j / 0.07, -10, 10 );  out = mean_i loss_i
//
// fb = f_hat * sqrt(log2e/0.07) in bf16 -> MFMA dot yields s/0.07*log2e directly;
// clamp at +-10*log2e (fmed3), single v_exp_f32 (exp2). Diagonal excluded exactly
// via wave-uniform tile check.
//
// R2 change: R1's VGPR_Count=48 proved fragments were NOT register-resident —
// the backend's occupancy-driven scheduler was reloading them from L2 every
// tile (75% stall, MfmaUtil 7%). Fix: amdgpu_waves_per_eu(2,4) to lift the
// register-pressure target, named fragment variables + macros (no arrays
// passed by pointer), fused finalize (single block, no memset/atomic).

using short8  = __attribute__((ext_vector_type(8))) short;   // 8 bf16 = 4 VGPRs
using floatx4 = __attribute__((ext_vector_type(4))) float;

constexpr int   Bn = 8192;
constexpr int   Dk = 128;
constexpr int   NSLICE = 32;               // j-slices (blockIdx.x)
constexpr float PRESCALE = 4.5398160f;     // sqrt(log2(e)/0.07)
constexpr float CLAMP    = 14.4269504f;    // 10*log2(e)
constexpr float LN2      = 0.69314718056f;

// ---- kernel 1: row L2-normalize, scale, cast to bf16 --------------------
__global__ __launch_bounds__(256) void normalize_k(
    const float* __restrict__ feat, unsigned short* __restrict__ fb) {
  const int row  = blockIdx.x * 4 + (threadIdx.x >> 6);
  const int lane = threadIdx.x & 63;
  const float2 v = ((const float2*)(feat + (size_t)row * Dk))[lane];
  float s = v.x * v.x + v.y * v.y;
#pragma unroll
  for (int m = 1; m < 64; m <<= 1) s += __shfl_xor(s, m);
  const float inv = PRESCALE / fmaxf(sqrtf(s), 1e-8f);
  __hip_bfloat16 b0 = __float2bfloat16(v.x * inv);
  __hip_bfloat16 b1 = __float2bfloat16(v.y * inv);
  ushort2 o;
  o.x = __builtin_bit_cast(unsigned short, b0);
  o.y = __builtin_bit_cast(unsigned short, b1);
  ((ushort2*)(fb + (size_t)row * Dk))[lane] = o;
}

// ---- kernel 2: tiled F*F^T with fused exp + masked row-sum --------------
// grid: (32 j-slices, 64 i-blocks). Block = 256 thr = 4 waves.
// Wave: 32 rows (A frags in named registers) x 256 cols, 16 col-tiles of 16.
// B frags direct from L2, register double-buffered via named vars.
__global__ __attribute__((amdgpu_waves_per_eu(2, 4))) __launch_bounds__(256)
void simloss_k(const unsigned short* __restrict__ fb,
               const int* __restrict__ labels,
               float* __restrict__ rowpos2, float* __restrict__ rowneg2) {
  const int lane  = threadIdx.x & 63;
  const int wave  = threadIdx.x >> 6;
  const int quad  = lane >> 4;
  const int lr    = lane & 15;
  const int ibase = blockIdx.y * 128 + wave * 32;   // rows [ibase, ibase+32)
  const int jbase = blockIdx.x * 256;               // cols [jbase, jbase+256)

  // A fragments, individually named: lane holds fb[ibase+t*16+lr][quad*8+kk*32 ..+8]
  const short* ap0 = (const short*)fb + (size_t)(ibase + lr) * Dk + quad * 8;
  const short* ap1 = ap0 + 16 * Dk;
  const short8 a0k0 = *(const short8*)(ap0 +  0);
  const short8 a0k1 = *(const short8*)(ap0 + 32);
  const short8 a0k2 = *(const short8*)(ap0 + 64);
  const short8 a0k3 = *(const short8*)(ap0 + 96);
  const short8 a1k0 = *(const short8*)(ap1 +  0);
  const short8 a1k1 = *(const short8*)(ap1 + 32);
  const short8 a1k2 = *(const short8*)(ap1 + 64);
  const short8 a1k3 = *(const short8*)(ap1 + 96);

  // labels of this lane's accumulator rows: row_in_tile = quad*4 + r
  const int li00 = labels[ibase + quad * 4 + 0];
  const int li01 = labels[ibase + quad * 4 + 1];
  const int li02 = labels[ibase + quad * 4 + 2];
  const int li03 = labels[ibase + quad * 4 + 3];
  const int li10 = labels[ibase + 16 + quad * 4 + 0];
  const int li11 = labels[ibase + 16 + quad * 4 + 1];
  const int li12 = labels[ibase + 16 + quad * 4 + 2];
  const int li13 = labels[ibase + 16 + quad * 4 + 3];

  const bool d0 = (quad * 4 + 0) == lr;
  const bool d1 = (quad * 4 + 1) == lr;
  const bool d2 = (quad * 4 + 2) == lr;
  const bool d3 = (quad * 4 + 3) == lr;

  float p00 = 0.f, p01 = 0.f, p02 = 0.f, p03 = 0.f;
  float p10 = 0.f, p11 = 0.f, p12 = 0.f, p13 = 0.f;
  float n00 = 0.f, n01 = 0.f, n02 = 0.f, n03 = 0.f;
  float n10 = 0.f, n11 = 0.f, n12 = 0.f, n13 = 0.f;

#define LOADB(JT, B0, B1, B2, B3, LJ)                                      \
  do {                                                                     \
    const int brow_ = jbase + (JT) * 16 + lr;                              \
    const short* bp_ = (const short*)fb + (size_t)brow_ * Dk + quad * 8;   \
    B0 = *(const short8*)(bp_ +  0);                                       \
    B1 = *(const short8*)(bp_ + 32);                                       \
    B2 = *(const short8*)(bp_ + 64);                                       \
    B3 = *(const short8*)(bp_ + 96);                                       \
    LJ = labels[brow_];                                                    \
  } while (0)

#define COMPUTE(JT, B0, B1, B2, B3, LJ)                                    \
  do {                                                                     \
    floatx4 acc0 = {0.f, 0.f, 0.f, 0.f};                                   \
    floatx4 acc1 = {0.f, 0.f, 0.f, 0.f};                                   \
    acc0 = __builtin_amdgcn_mfma_f32_16x16x32_bf16(a0k0, B0, acc0, 0, 0, 0); \
    acc1 = __builtin_amdgcn_mfma_f32_16x16x32_bf16(a1k0, B0, acc1, 0, 0, 0); \
    acc0 = __builtin_amdgcn_mfma_f32_16x16x32_bf16(a0k1, B1, acc0, 0, 0, 0); \
    acc1 = __builtin_amdgcn_mfma_f32_16x16x32_bf16(a1k1, B1, acc1, 0, 0, 0); \
    acc0 = __builtin_amdgcn_mfma_f32_16x16x32_bf16(a0k2, B2, acc0, 0, 0, 0); \
    acc1 = __builtin_amdgcn_mfma_f32_16x16x32_bf16(a1k2, B2, acc1, 0, 0, 0); \
    acc0 = __builtin_amdgcn_mfma_f32_16x16x32_bf16(a0k3, B3, acc0, 0, 0, 0); \
    acc1 = __builtin_amdgcn_mfma_f32_16x16x32_bf16(a1k3, B3, acc1, 0, 0, 0); \
    const int j0_ = jbase + (JT) * 16;                                     \
    float e0, e1, e2, e3;                                                  \
    /* tile t=0 */                                                         \
    e0 = __builtin_amdgcn_exp2f(__builtin_amdgcn_fmed3f(acc0[0], -CLAMP, CLAMP)); \
    e1 = __builtin_amdgcn_exp2f(__builtin_amdgcn_fmed3f(acc0[1], -CLAMP, CLAMP)); \
    e2 = __builtin_amdgcn_exp2f(__builtin_amdgcn_fmed3f(acc0[2], -CLAMP, CLAMP)); \
    e3 = __builtin_amdgcn_exp2f(__builtin_amdgcn_fmed3f(acc0[3], -CLAMP, CLAMP)); \
    if (j0_ == ibase) {                                                    \
      if (d0) e0 = 0.f;                                                    \
      if (d1) e1 = 0.f;                                                    \
      if (d2) e2 = 0.f;                                                    \
      if (d3) e3 = 0.f;                                                    \
    }                                                                      \
    n00 += e0; n01 += e1; n02 += e2; n03 += e3;                            \
    p00 += (li00 == LJ) ? e0 : 0.f;                                        \
    p01 += (li01 == LJ) ? e1 : 0.f;                                        \
    p02 += (li02 == LJ) ? e2 : 0.f;                                        \
    p03 += (li03 == LJ) ? e3 : 0.f;                                        \
    /* tile t=1 */                                                         \
    e0 = __builtin_amdgcn_exp2f(__builtin_amdgcn_fmed3f(acc1[0], -CLAMP, CLAMP)); \
    e1 = __builtin_amdgcn_exp2f(__builtin_amdgcn_fmed3f(acc1[1], -CLAMP, CLAMP)); \
    e2 = __builtin_amdgcn_exp2f(__builtin_amdgcn_fmed3f(acc1[2], -CLAMP, CLAMP)); \
    e3 = __builtin_amdgcn_exp2f(__builtin_amdgcn_fmed3f(acc1[3], -CLAMP, CLAMP)); \
    if (j0_ == ibase + 16) {                                               \
      if (d0) e0 = 0.f;                                                    \
      if (d1) e1 = 0.f;                                                    \
      if (d2) e2 = 0.f;                                                    \
      if (d3) e3 = 0.f;                                                    \
    }                                                                      \
    n10 += e0; n11 += e1; n12 += e2; n13 += e3;                            \
    p10 += (li10 == LJ) ? e0 : 0.f;                                        \
    p11 += (li11 == LJ) ? e1 : 0.f;                                        \
    p12 += (li12 == LJ) ? e2 : 0.f;                                        \
    p13 += (li13 == LJ) ? e3 : 0.f;                                        \
  } while (0)

  // software pipeline: double-buffered named B fragments, unroll-by-2
  short8 b00, b01, b02, b03, b10, b11, b12, b13;
  int lj0, lj1;
  LOADB(0, b00, b01, b02, b03, lj0);
#pragma unroll 1
  for (int jt = 0; jt < 16; jt += 2) {
    LOADB(jt + 1, b10, b11, b12, b13, lj1);
    COMPUTE(jt, b00, b01, b02, b03, lj0);
    const int jn = (jt + 2 < 16) ? jt + 2 : 0;   // clamp: avoid OOB prefetch
    LOADB(jn, b00, b01, b02, b03, lj0);
    COMPUTE(jt + 1, b10, b11, b12, b13, lj1);
  }
#undef LOADB
#undef COMPUTE

  // reduce across the 16 lanes of a col-group (xor 1,2,4,8 stays in group);
  // unique (slice,row) writer -> plain stores, no atomics, no memset
  float pr[8] = {p00, p01, p02, p03, p10, p11, p12, p13};
  float nr[8] = {n00, n01, n02, n03, n10, n11, n12, n13};
#pragma unroll
  for (int idx = 0; idx < 8; ++idx) {
    float p = pr[idx], n = nr[idx];
#pragma unroll
    for (int m = 1; m < 16; m <<= 1) {
      p += __shfl_xor(p, m);
      n += __shfl_xor(n, m);
    }
    if (lr == 0) {
      const int row = ibase + (idx >> 2) * 16 + quad * 4 + (idx & 3);
      rowpos2[(size_t)blockIdx.x * Bn + row] = p;
      rowneg2[(size_t)blockIdx.x * Bn + row] = n;
    }
  }
}

// ---- kernel 3: single block — sum slice partials, per-row loss, mean -----
__global__ __launch_bounds__(1024) void finalize_k(
    const float* __restrict__ rowpos2, const float* __restrict__ rowneg2,
    float* __restrict__ out) {
  float acc = 0.f;
#pragma unroll
  for (int g = 0; g < 2; ++g) {
    const int grow = g * 4096 + threadIdx.x * 4;
    float4 p = {0.f, 0.f, 0.f, 0.f}, n = {0.f, 0.f, 0.f, 0.f};
    for (int s = 0; s < NSLICE; ++s) {
      const float4 pp = *(const float4*)(rowpos2 + (size_t)s * Bn + grow);
      const float4 nn = *(const float4*)(rowneg2 + (size_t)s * Bn + grow);
      p.x += pp.x; p.y += pp.y; p.z += pp.z; p.w += pp.w;
      n.x += nn.x; n.y += nn.y; n.z += nn.z; n.w += nn.w;
    }
    acc += LN2 * (__builtin_amdgcn_logf(fmaxf(n.x, 1e-8f)) - __builtin_amdgcn_logf(fmaxf(p.x, 1e-8f)));
    acc += LN2 * (__builtin_amdgcn_logf(fmaxf(n.y, 1e-8f)) - __builtin_amdgcn_logf(fmaxf(p.y, 1e-8f)));
    acc += LN2 * (__builtin_amdgcn_logf(fmaxf(n.z, 1e-8f)) - __builtin_amdgcn_logf(fmaxf(p.z, 1e-8f)));
    acc += LN2 * (__builtin_amdgcn_logf(fmaxf(n.w, 1e-8f)) - __builtin_amdgcn_logf(fmaxf(p.w, 1e-8f)));
  }
#pragma unroll
  for (int m = 1; m < 64; m <<= 1) acc += __shfl_xor(acc, m);
  __shared__ float part[16];
  const int lane = threadIdx.x & 63, w = threadIdx.x >> 6;
  if (lane == 0) part[w] = acc;
  __syncthreads();
  if (threadIdx.x == 0) {
    float s = 0.f;
#pragma unroll
    for (int i = 0; i < 16; ++i) s += part[i];
    *out = s * (1.0f / (float)Bn);
  }
}

extern "C" void kernel_launch(void* const* d_in, const int* in_sizes, int n_in,
                              void* d_out, int out_size, void* d_ws, size_t ws_size,
                              hipStream_t stream) {
  const float* feat   = (const float*)d_in[0];
  const int*   labels = (const int*)d_in[1];
  float* out = (float*)d_out;

  // ws layout: [0, 2MB) bf16 fb[8192][128]; then rowpos2[32][8192], rowneg2[32][8192]
  unsigned short* fb = (unsigned short*)d_ws;
  float* rowpos2 = (float*)((char*)d_ws + (size_t)Bn * Dk * sizeof(unsigned short));
  float* rowneg2 = rowpos2 + (size_t)NSLICE * Bn;

  normalize_k<<<Bn / 4, 256, 0, stream>>>(feat, fb);
  dim3 grid(NSLICE, 64);  // x = j-slice, y = i-block
  simloss_k<<<grid, 256, 0, stream>>>(fb, labels, rowpos2, rowneg2);
  finalize_k<<<1, 1024, 0, stream>>>(rowpos2, rowneg2, out);
}

// Round 4
// 112.845 us; speedup vs baseline: 1.3514x; 1.3514x over previous
//
#include <hip/hip_runtime.h>
#include <hip/hip_bf16.h>

// ContrastiveLoss: B=8192, D=128, 100 classes.
// loss_i = -log( max(sum_{j!=i, lab_j==lab_i} e^{s_ij},1e-8) / max(sum_{j!=i} e^{s_ij},1e-8) )
// s_ij = clip( f_hat_i . f_hat_j / 0.07, -10, 10 );  out = mean_i loss_i
//
// fb = f_hat * sqrt(log2e/0.07) in bf16 -> MFMA dot yields s/0.07*log2e directly;
// clamp at +-10*log2e (fmed3), single v_exp_f32 (exp2). Diagonal excluded exactly
// via wave-uniform tile check.
//
// R3 change: R1/R2 proved the in-loop L2 B-loads can't be pipelined by the
// compiler (VGPR stuck at 48-60, both pipes <25% busy = vmcnt stall). New
// structure: stage the block's 256-row B slice in LDS once (64 KB, XOR-16B
// chunk swizzle -> 2-way bank aliasing = free), then the fully-unrolled tile
// loop feeds MFMA from conflict-free ds_read_b128 only. Column labels live in
// 16 registers. Finalize back to distributed 32-block form.

using short8  = __attribute__((ext_vector_type(8))) short;   // 8 bf16 = 4 VGPRs
using floatx4 = __attribute__((ext_vector_type(4))) float;

constexpr int   Bn = 8192;
constexpr int   Dk = 128;
constexpr int   NSLICE = 32;               // j-slices (blockIdx.x)
constexpr float PRESCALE = 4.5398160f;     // sqrt(log2(e)/0.07)
constexpr float CLAMP    = 14.4269504f;    // 10*log2(e)
constexpr float LN2      = 0.69314718056f;

// ---- kernel 1: row L2-normalize, scale, cast to bf16 --------------------
__global__ __launch_bounds__(256) void normalize_k(
    const float* __restrict__ feat, unsigned short* __restrict__ fb) {
  const int row  = blockIdx.x * 4 + (threadIdx.x >> 6);
  const int lane = threadIdx.x & 63;
  const float2 v = ((const float2*)(feat + (size_t)row * Dk))[lane];
  float s = v.x * v.x + v.y * v.y;
#pragma unroll
  for (int m = 1; m < 64; m <<= 1) s += __shfl_xor(s, m);
  const float inv = PRESCALE / fmaxf(sqrtf(s), 1e-8f);
  __hip_bfloat16 b0 = __float2bfloat16(v.x * inv);
  __hip_bfloat16 b1 = __float2bfloat16(v.y * inv);
  ushort2 o;
  o.x = __builtin_bit_cast(unsigned short, b0);
  o.y = __builtin_bit_cast(unsigned short, b1);
  ((ushort2*)(fb + (size_t)row * Dk))[lane] = o;
}

// ---- kernel 2: tiled F*F^T with fused exp + masked row-sum --------------
// grid: (32 j-slices, 64 i-blocks). Block = 256 thr = 4 waves.
// Block stages B slice (256 rows x 128 bf16 = 64 KB) in LDS with 16B-chunk
// XOR swizzle; each wave then does 32 rows x 256 cols from registers + LDS.
__global__ __launch_bounds__(256, 2) void simloss_k(
    const unsigned short* __restrict__ fb, const int* __restrict__ labels,
    float* __restrict__ rowpos2, float* __restrict__ rowneg2) {
  __shared__ __align__(16) short Bsh[256 * Dk];   // 65536 B (static LDS limit)

  const int t     = threadIdx.x;
  const int lane  = t & 63;
  const int wave  = t >> 6;
  const int quad  = lane >> 4;
  const int lr    = lane & 15;
  const int ibase = blockIdx.y * 128 + wave * 32;   // rows [ibase, ibase+32)
  const int jbase = blockIdx.x * 256;               // cols [jbase, jbase+256)

  // ---- stage B slice into LDS, swizzled: chunk c of row r -> c ^ (r&7) ----
  {
    const int chunk = t & 15;        // 16B chunk within a 256B row
    const int r0    = t >> 4;        // rows r0, r0+16, ... (lanes 0-15 share a row)
#pragma unroll
    for (int it = 0; it < 16; ++it) {
      const int row = r0 + it * 16;
      const short8 v = *(const short8*)((const short*)fb +
                          (size_t)(jbase + row) * Dk + chunk * 8);
      *(short8*)(Bsh + row * Dk + ((chunk ^ (row & 7)) * 8)) = v;
    }
  }

  // ---- A fragments (named, register-resident) -----------------------------
  const short* ap0 = (const short*)fb + (size_t)(ibase + lr) * Dk + quad * 8;
  const short* ap1 = ap0 + 16 * Dk;
  const short8 a0k0 = *(const short8*)(ap0 +  0);
  const short8 a0k1 = *(const short8*)(ap0 + 32);
  const short8 a0k2 = *(const short8*)(ap0 + 64);
  const short8 a0k3 = *(const short8*)(ap0 + 96);
  const short8 a1k0 = *(const short8*)(ap1 +  0);
  const short8 a1k1 = *(const short8*)(ap1 + 32);
  const short8 a1k2 = *(const short8*)(ap1 + 64);
  const short8 a1k3 = *(const short8*)(ap1 + 96);

  // row labels (accumulator rows: row_in_tile = quad*4 + r)
  const int li00 = labels[ibase + quad * 4 + 0];
  const int li01 = labels[ibase + quad * 4 + 1];
  const int li02 = labels[ibase + quad * 4 + 2];
  const int li03 = labels[ibase + quad * 4 + 3];
  const int li10 = labels[ibase + 16 + quad * 4 + 0];
  const int li11 = labels[ibase + 16 + quad * 4 + 1];
  const int li12 = labels[ibase + 16 + quad * 4 + 2];
  const int li13 = labels[ibase + 16 + quad * 4 + 3];

  // column labels for this lane, one per tile (full unroll keeps in regs)
  int labj[16];
#pragma unroll
  for (int jt = 0; jt < 16; ++jt) labj[jt] = labels[jbase + jt * 16 + lr];

  const bool d0 = (quad * 4 + 0) == lr;
  const bool d1 = (quad * 4 + 1) == lr;
  const bool d2 = (quad * 4 + 2) == lr;
  const bool d3 = (quad * 4 + 3) == lr;

  // per-lane swizzled chunk offsets (constant across jt), in shorts
  const int sw = lr & 7;
  const int c0 = (( 0 + quad) ^ sw) * 8;
  const int c1 = (( 4 + quad) ^ sw) * 8;
  const int c2 = (( 8 + quad) ^ sw) * 8;
  const int c3 = ((12 + quad) ^ sw) * 8;

  float p00 = 0.f, p01 = 0.f, p02 = 0.f, p03 = 0.f;
  float p10 = 0.f, p11 = 0.f, p12 = 0.f, p13 = 0.f;
  float n00 = 0.f, n01 = 0.f, n02 = 0.f, n03 = 0.f;
  float n10 = 0.f, n11 = 0.f, n12 = 0.f, n13 = 0.f;

  __syncthreads();

#pragma unroll
  for (int jt = 0; jt < 16; ++jt) {
    const short* bp = Bsh + (jt * 16 + lr) * Dk;
    const short8 B0 = *(const short8*)(bp + c0);
    const short8 B1 = *(const short8*)(bp + c1);
    const short8 B2 = *(const short8*)(bp + c2);
    const short8 B3 = *(const short8*)(bp + c3);

    floatx4 acc0 = {0.f, 0.f, 0.f, 0.f};
    floatx4 acc1 = {0.f, 0.f, 0.f, 0.f};
    acc0 = __builtin_amdgcn_mfma_f32_16x16x32_bf16(a0k0, B0, acc0, 0, 0, 0);
    acc1 = __builtin_amdgcn_mfma_f32_16x16x32_bf16(a1k0, B0, acc1, 0, 0, 0);
    acc0 = __builtin_amdgcn_mfma_f32_16x16x32_bf16(a0k1, B1, acc0, 0, 0, 0);
    acc1 = __builtin_amdgcn_mfma_f32_16x16x32_bf16(a1k1, B1, acc1, 0, 0, 0);
    acc0 = __builtin_amdgcn_mfma_f32_16x16x32_bf16(a0k2, B2, acc0, 0, 0, 0);
    acc1 = __builtin_amdgcn_mfma_f32_16x16x32_bf16(a1k2, B2, acc1, 0, 0, 0);
    acc0 = __builtin_amdgcn_mfma_f32_16x16x32_bf16(a0k3, B3, acc0, 0, 0, 0);
    acc1 = __builtin_amdgcn_mfma_f32_16x16x32_bf16(a1k3, B3, acc1, 0, 0, 0);

    const int j0 = jbase + jt * 16;
    const int lj = labj[jt];
    float e0, e1, e2, e3;
    // tile t=0
    e0 = __builtin_amdgcn_exp2f(__builtin_amdgcn_fmed3f(acc0[0], -CLAMP, CLAMP));
    e1 = __builtin_amdgcn_exp2f(__builtin_amdgcn_fmed3f(acc0[1], -CLAMP, CLAMP));
    e2 = __builtin_amdgcn_exp2f(__builtin_amdgcn_fmed3f(acc0[2], -CLAMP, CLAMP));
    e3 = __builtin_amdgcn_exp2f(__builtin_amdgcn_fmed3f(acc0[3], -CLAMP, CLAMP));
    if (j0 == ibase) {                 // wave-uniform: tile on diagonal
      if (d0) e0 = 0.f;
      if (d1) e1 = 0.f;
      if (d2) e2 = 0.f;
      if (d3) e3 = 0.f;
    }
    n00 += e0; n01 += e1; n02 += e2; n03 += e3;
    p00 += (li00 == lj) ? e0 : 0.f;
    p01 += (li01 == lj) ? e1 : 0.f;
    p02 += (li02 == lj) ? e2 : 0.f;
    p03 += (li03 == lj) ? e3 : 0.f;
    // tile t=1
    e0 = __builtin_amdgcn_exp2f(__builtin_amdgcn_fmed3f(acc1[0], -CLAMP, CLAMP));
    e1 = __builtin_amdgcn_exp2f(__builtin_amdgcn_fmed3f(acc1[1], -CLAMP, CLAMP));
    e2 = __builtin_amdgcn_exp2f(__builtin_amdgcn_fmed3f(acc1[2], -CLAMP, CLAMP));
    e3 = __builtin_amdgcn_exp2f(__builtin_amdgcn_fmed3f(acc1[3], -CLAMP, CLAMP));
    if (j0 == ibase + 16) {
      if (d0) e0 = 0.f;
      if (d1) e1 = 0.f;
      if (d2) e2 = 0.f;
      if (d3) e3 = 0.f;
    }
    n10 += e0; n11 += e1; n12 += e2; n13 += e3;
    p10 += (li10 == lj) ? e0 : 0.f;
    p11 += (li11 == lj) ? e1 : 0.f;
    p12 += (li12 == lj) ? e2 : 0.f;
    p13 += (li13 == lj) ? e3 : 0.f;
  }

  // reduce across the 16 lanes of a col-group (xor 1,2,4,8 stays in group);
  // unique (slice,row) writer -> plain stores, no atomics, no memset
  float pr[8] = {p00, p01, p02, p03, p10, p11, p12, p13};
  float nr[8] = {n00, n01, n02, n03, n10, n11, n12, n13};
#pragma unroll
  for (int idx = 0; idx < 8; ++idx) {
    float p = pr[idx], n = nr[idx];
#pragma unroll
    for (int m = 1; m < 16; m <<= 1) {
      p += __shfl_xor(p, m);
      n += __shfl_xor(n, m);
    }
    if (lr == 0) {
      const int row = ibase + (idx >> 2) * 16 + quad * 4 + (idx & 3);
      rowpos2[(size_t)blockIdx.x * Bn + row] = p;
      rowneg2[(size_t)blockIdx.x * Bn + row] = n;
    }
  }
}

// ---- kernel 3: sum slice partials, per-row loss, mean (distributed) ------
__global__ __launch_bounds__(256) void finalize_k(
    const float* __restrict__ rowpos2, const float* __restrict__ rowneg2,
    float* __restrict__ out) {
  const int row = blockIdx.x * 256 + threadIdx.x;
  float p = 0.f, n = 0.f;
#pragma unroll
  for (int s = 0; s < NSLICE; ++s) {       // coalesced: consecutive rows adjacent
    p += rowpos2[(size_t)s * Bn + row];
    n += rowneg2[(size_t)s * Bn + row];
  }
  p = fmaxf(p, 1e-8f);
  n = fmaxf(n, 1e-8f);
  float loss = LN2 * (__builtin_amdgcn_logf(n) - __builtin_amdgcn_logf(p));
#pragma unroll
  for (int m = 1; m < 64; m <<= 1) loss += __shfl_xor(loss, m);
  __shared__ float partial[4];
  const int lane = threadIdx.x & 63, w = threadIdx.x >> 6;
  if (lane == 0) partial[w] = loss;
  __syncthreads();
  if (threadIdx.x == 0) {
    const float s = partial[0] + partial[1] + partial[2] + partial[3];
    atomicAdd(out, s * (1.0f / (float)Bn));
  }
}

extern "C" void kernel_launch(void* const* d_in, const int* in_sizes, int n_in,
                              void* d_out, int out_size, void* d_ws, size_t ws_size,
                              hipStream_t stream) {
  const float* feat   = (const float*)d_in[0];
  const int*   labels = (const int*)d_in[1];
  float* out = (float*)d_out;

  // ws layout: [0, 2MB) bf16 fb[8192][128]; then rowpos2[32][8192], rowneg2[32][8192]
  unsigned short* fb = (unsigned short*)d_ws;
  float* rowpos2 = (float*)((char*)d_ws + (size_t)Bn * Dk * sizeof(unsigned short));
  float* rowneg2 = rowpos2 + (size_t)NSLICE * Bn;

  hipMemsetAsync(out, 0, sizeof(float), stream);

  normalize_k<<<Bn / 4, 256, 0, stream>>>(feat, fb);
  dim3 grid(NSLICE, 64);  // x = j-slice, y = i-block
  simloss_k<<<grid, 256, 0, stream>>>(fb, labels, rowpos2, rowneg2);
  finalize_k<<<Bn / 256, 256, 0, stream>>>(rowpos2, rowneg2, out);
}